// Round 10
// baseline (3639.311 us; speedup 1.0000x reference)
//
#include <hip/hip_runtime.h>
#include <math.h>

#define D64 64
#define NBATCH 8
#define CBAND 2.0f
#define CHUNK 128                 // codes per LDS chunk (16 KB)
#define NCHUNK 64                 // K / CHUNK

typedef short s16x8 __attribute__((ext_vector_type(8)));   // 8 bf16 (bit pattern)
typedef float f32x4 __attribute__((ext_vector_type(4)));

#define GLOAD16(g, l) __builtin_amdgcn_global_load_lds( \
    (const __attribute__((address_space(1))) unsigned*)(g), \
    (__attribute__((address_space(3))) unsigned*)(l), 16, 0, 0)
#define GLOAD4(g, l) __builtin_amdgcn_global_load_lds( \
    (const __attribute__((address_space(1))) unsigned*)(g), \
    (__attribute__((address_space(3))) unsigned*)(l), 4, 0, 0)

__device__ inline short f2bf(float f) {
  unsigned u = __builtin_bit_cast(unsigned, f);
  unsigned r = (u + 0x7FFFu + ((u >> 16) & 1u)) >> 16;
  return (short)r;
}

// ---------------- c_sq + bf16 convert + workspace zeroing ----------------
__global__ __launch_bounds__(256) void csq_cvt_kernel(
    const float* __restrict__ cb, float* __restrict__ csq,
    short* __restrict__ cbh,
    unsigned int* __restrict__ counts, double* __restrict__ sse, int K) {
  int t = blockIdx.x * blockDim.x + threadIdx.x;
  if (t < NBATCH * K) counts[t] = 0u;
  if (t == 0) *sse = 0.0;
  int row = t >> 6, lane = t & 63;
  if (row >= K) return;
  float v = cb[(size_t)row * D64 + lane];
  cbh[(size_t)row * D64 + lane] = f2bf(v);
  v *= v;
  #pragma unroll
  for (int off = 32; off; off >>= 1) v += __shfl_xor(v, off, 64);
  if (lane == 0) csq[row] = v;
}

// -------- single-sweep filter: per-(point, chunk) bf16-score min --------
// block = 4 waves x 32 points = 128 points, full K, LDS-staged codebook.
// 2-deep buffers + counted vmcnt + raw barriers.
// Every thread issues exactly 5 staging loads per chunk (uniform vmcnt).
__global__ __launch_bounds__(256, 2) void chunkmin_kernel(
    const float* __restrict__ z, const short* __restrict__ cbh,
    const float* __restrict__ csq, float* __restrict__ bm, int N, int K) {
  __shared__ short lcb[2][CHUNK * D64];     // 2 x 16 KB
  __shared__ float lcsq[2][CHUNK];          // 2 x 512 B

  int w = threadIdx.x >> 6;
  int l = threadIdx.x & 63;
  int lr = l & 15, lg = l >> 4;
  int base = blockIdx.x * 128 + w * 32;

  // ---- A fragments (z rows) ----
  s16x8 A[2][2];
  #pragma unroll
  for (int rt = 0; rt < 2; ++rt) {
    int row = base + rt * 16 + lr;
    #pragma unroll
    for (int kh = 0; kh < 2; ++kh) {
      const float4* zp = reinterpret_cast<const float4*>(
          z + (size_t)row * D64 + kh * 32 + lg * 8);
      float4 p0 = zp[0], p1 = zp[1];
      s16x8 t;
      t[0] = f2bf(p0.x); t[1] = f2bf(p0.y); t[2] = f2bf(p0.z); t[3] = f2bf(p0.w);
      t[4] = f2bf(p1.x); t[5] = f2bf(p1.y); t[6] = f2bf(p1.z); t[7] = f2bf(p1.w);
      A[rt][kh] = t;
    }
  }

  // per-lane swizzled LDS read offsets (constant over inner iters)
  int sw = (lr & 7) << 4;
  int p0off = ((lr * 128 + lg * 16) ^ sw);
  int p1off = ((lr * 128 + 64 + lg * 16) ^ sw);
  int swl = (l >> 3) << 4;                  // staging source swizzle

  const char* cbbytes = (const char*)cbh;
  // STAGE: 4x GLOAD16 (cbh chunk, pre-swizzled source) + 1x GLOAD4 (csq).
  // waves 2,3 duplicate waves 0,1's csq load (same src+dst) for uniform vmcnt.
#define STAGE(chunk, b)                                                       \
  {                                                                           \
    const char* src = cbbytes + (size_t)(chunk) * (CHUNK * 128);              \
    char* dstb = (char*)lcb[b];                                               \
    _Pragma("unroll")                                                         \
    for (int j = 0; j < 4; ++j) {                                             \
      int X = (w * 4 + j) * 1024 + l * 16;                                    \
      GLOAD16(src + (X ^ swl), dstb + (w * 4 + j) * 1024);                    \
    }                                                                         \
    const char* csrc = (const char*)(csq + (chunk) * CHUNK) + (w & 1) * 256;  \
    GLOAD4(csrc + l * 4, (char*)lcsq[b] + (w & 1) * 256);                     \
  }

  // compute chunk c out of buffer b: per-point chunk-min -> bm
  auto do_chunk = [&](int c, int b) {
    const char* pb0 = (const char*)lcb[b] + p0off;
    const char* pb1 = (const char*)lcb[b] + p1off;
    const float* cqb = lcsq[b] + lr;
    float rmin[2][4];
    #pragma unroll
    for (int rt = 0; rt < 2; ++rt)
      #pragma unroll
      for (int r = 0; r < 4; ++r) rmin[rt][r] = INFINITY;
    #pragma unroll
    for (int i = 0; i < 8; ++i) {
      s16x8 B0 = *(const s16x8*)(pb0 + i * 2048);
      s16x8 B1 = *(const s16x8*)(pb1 + i * 2048);
      float cq = cqb[i * 16];
      #pragma unroll
      for (int rt = 0; rt < 2; ++rt) {
        f32x4 acc = {0.f, 0.f, 0.f, 0.f};
        acc = __builtin_amdgcn_mfma_f32_16x16x32_bf16(A[rt][0], B0, acc, 0, 0, 0);
        acc = __builtin_amdgcn_mfma_f32_16x16x32_bf16(A[rt][1], B1, acc, 0, 0, 0);
        #pragma unroll
        for (int r = 0; r < 4; ++r) {
          float s = fmaf(-2.0f, acc[r], cq);
          rmin[rt][r] = fminf(rmin[rt][r], s);
        }
      }
    }
    // reduce over the 16 code-cols (lane bits 0..3) -> chunk-min, store
    #pragma unroll
    for (int rt = 0; rt < 2; ++rt)
      #pragma unroll
      for (int r = 0; r < 4; ++r) {
        float x = rmin[rt][r];
        x = fminf(x, __shfl_xor(x, 1, 64));
        x = fminf(x, __shfl_xor(x, 2, 64));
        x = fminf(x, __shfl_xor(x, 4, 64));
        x = fminf(x, __shfl_xor(x, 8, 64));
        if (lr == 0)
          bm[(size_t)(base + rt * 16 + lg * 4 + r) * NCHUNK + c] = x;
      }
  };

  // prologue
  STAGE(0, 0);
  // main loop: chunks 0..NCHUNK-2, staging c+1 each iter.
  // wait vmcnt(5): chunk c's 5 loads done, chunk c+1's 5 stay in flight.
  for (int c = 0; c < NCHUNK - 1; ++c) {
    STAGE(c + 1, (c + 1) & 1);
    asm volatile("s_waitcnt vmcnt(5)" ::: "memory");
    __builtin_amdgcn_sched_barrier(0);
    __builtin_amdgcn_s_barrier();
    do_chunk(c, c & 1);
    asm volatile("s_waitcnt lgkmcnt(0)" ::: "memory");
    __builtin_amdgcn_sched_barrier(0);
    __builtin_amdgcn_s_barrier();
  }
  // epilogue: last chunk
  asm volatile("s_waitcnt vmcnt(0)" ::: "memory");
  __builtin_amdgcn_sched_barrier(0);
  __builtin_amdgcn_s_barrier();
  do_chunk(NCHUNK - 1, (NCHUNK - 1) & 1);
#undef STAGE
}

// ---- exact fp32 rescan of qualifying chunks + fp64 tiebreak + outputs ----
__global__ __launch_bounds__(256) void rescore_quant_kernel(
    const float* __restrict__ z, const float* __restrict__ cb,
    const float* __restrict__ csq, const float* __restrict__ bm,
    const int* __restrict__ batch_raw,
    float* __restrict__ out_idx, float* __restrict__ outq,
    unsigned int* __restrict__ counts, double* __restrict__ sse,
    int N, int K) {
  __shared__ double red[4];
  int n = blockIdx.x * blockDim.x + threadIdx.x;

  const float4* z4 = reinterpret_cast<const float4*>(z) + (size_t)n * 16;
  float4 zr[16];
  #pragma unroll
  for (int d = 0; d < 16; ++d) zr[d] = z4[d];

  // pass 1: global bf16-score min over the 64 chunk-mins
  const float4* bmv = reinterpret_cast<const float4*>(bm + (size_t)n * NCHUNK);
  float m = INFINITY;
  #pragma unroll
  for (int i = 0; i < 16; ++i) {
    float4 b = bmv[i];
    m = fminf(m, fminf(fminf(b.x, b.y), fminf(b.z, b.w)));
  }
  float thr = m + CBAND;

  // pass 2: exact fp32 rescan of every code in qualifying chunks
  float b1 = INFINITY, b2 = INFINITY;
  int i1 = 0x7FFFFFFF, i2 = 0x7FFFFFFF;
  #pragma unroll
  for (int i = 0; i < 16; ++i) {
    float4 bq = bmv[i];
    #pragma unroll
    for (int j = 0; j < 4; ++j) {
      float bv = (j == 0) ? bq.x : (j == 1) ? bq.y : (j == 2) ? bq.z : bq.w;
      if (bv <= thr) {
        int c = i * 4 + j;
        int k0 = c * CHUNK / 2;              // CHUNK codes per bm entry? no:
        // bm granularity is CHUNK codes per chunk (128), NCHUNK=64 chunks
        k0 = c * CHUNK;
        for (int kk = 0; kk < CHUNK; kk += 2) {
          int ka = k0 + kk;
          const float4* c0 = reinterpret_cast<const float4*>(cb) + (size_t)ka * 16;
          const float4* c1 = c0 + 16;
          float4 a0 = {0.f, 0.f, 0.f, 0.f}, a1 = {0.f, 0.f, 0.f, 0.f};
          #pragma unroll
          for (int d = 0; d < 16; ++d) {
            float4 q0 = c0[d], q1 = c1[d], zz = zr[d];
            a0.x = fmaf(q0.x, zz.x, a0.x);
            a0.y = fmaf(q0.y, zz.y, a0.y);
            a0.z = fmaf(q0.z, zz.z, a0.z);
            a0.w = fmaf(q0.w, zz.w, a0.w);
            a1.x = fmaf(q1.x, zz.x, a1.x);
            a1.y = fmaf(q1.y, zz.y, a1.y);
            a1.z = fmaf(q1.z, zz.z, a1.z);
            a1.w = fmaf(q1.w, zz.w, a1.w);
          }
          float s0 = csq[ka]     - 2.0f * ((a0.x + a0.y) + (a0.z + a0.w));
          float s1 = csq[ka + 1] - 2.0f * ((a1.x + a1.y) + (a1.z + a1.w));
          // top-2, strict < keeps lowest index on exact ties (sequential k)
          bool lt1 = s0 < b1;
          float cand = lt1 ? b1 : s0; int ci = lt1 ? i1 : ka;
          b1 = lt1 ? s0 : b1;  i1 = lt1 ? ka : i1;
          bool lt2 = cand < b2;
          b2 = lt2 ? cand : b2; i2 = lt2 ? ci : i2;
          lt1 = s1 < b1;
          cand = lt1 ? b1 : s1; ci = lt1 ? i1 : (ka + 1);
          b1 = lt1 ? s1 : b1;  i1 = lt1 ? (ka + 1) : i1;
          lt2 = cand < b2;
          b2 = lt2 ? cand : b2; i2 = lt2 ? ci : i2;
        }
      }
    }
  }

  int final_i = i1;
  if (i2 != 0x7FFFFFFF && (b2 - b1) < 1e-3f) {
    const float* zp  = z  + (size_t)n  * D64;
    const float* c1p = cb + (size_t)i1 * D64;
    const float* c2p = cb + (size_t)i2 * D64;
    double d0 = 0.0, d1 = 0.0;
    for (int d = 0; d < D64; ++d) {
      double t0 = (double)zp[d] - (double)c1p[d];
      double t1 = (double)zp[d] - (double)c2p[d];
      d0 += t0 * t0;
      d1 += t1 * t1;
    }
    if (d1 < d0 || (d1 == d0 && i2 < i1)) final_i = i2;
  }

  out_idx[n] = (float)final_i;

  int is64 = (batch_raw[N - 1] == 0) ? 1 : 0;
  int b = is64 ? batch_raw[2 * n] : batch_raw[n];
  atomicAdd(&counts[(size_t)b * K + final_i], 1u);

  // ---- quantize + straight-through + SSE (z row already in registers) ----
  const float4* cr = reinterpret_cast<const float4*>(cb) + (size_t)final_i * 16;
  float4* oq = reinterpret_cast<float4*>(outq) + (size_t)n * 16;
  double local = 0.0;
  #pragma unroll
  for (int d = 0; d < 16; ++d) {
    float4 q = cr[d], zz = zr[d];
    float4 t = {q.x - zz.x, q.y - zz.y, q.z - zz.z, q.w - zz.w};
    float4 st = {zz.x + t.x, zz.y + t.y, zz.z + t.z, zz.w + t.w};
    oq[d] = st;
    local += (double)t.x * t.x + (double)t.y * t.y +
             (double)t.z * t.z + (double)t.w * t.w;
  }
  #pragma unroll
  for (int off = 32; off; off >>= 1) local += __shfl_xor(local, off, 64);
  int lane = threadIdx.x & 63, wv = threadIdx.x >> 6;
  if (lane == 0) red[wv] = local;
  __syncthreads();
  if (threadIdx.x == 0) atomicAdd(sse, red[0] + red[1] + red[2] + red[3]);
}

// ---------------- per-batch entropy / perplexity / unique ----------------
__global__ __launch_bounds__(256) void stats_kernel(
    const unsigned int* __restrict__ counts,
    double* __restrict__ perp, double* __restrict__ ent,
    double* __restrict__ uniq, int K) {
  __shared__ double sh4[4], she[4], shu[4];
  int b = blockIdx.x;
  const unsigned int* c = counts + (size_t)b * K;
  int lane = threadIdx.x & 63, w = threadIdx.x >> 6;

  double tot = 0.0;
  for (int k = threadIdx.x; k < K; k += blockDim.x) tot += (double)c[k];
  #pragma unroll
  for (int off = 32; off; off >>= 1) tot += __shfl_xor(tot, off, 64);
  if (lane == 0) sh4[w] = tot;
  __syncthreads();
  double total = sh4[0] + sh4[1] + sh4[2] + sh4[3];
  double denom = fmax(total, 1.0);

  double e = 0.0, u = 0.0;
  for (int k = threadIdx.x; k < K; k += blockDim.x) {
    double cc = (double)c[k];
    double p = cc / denom;
    e -= p * log(p + 1e-10);
    if (cc > 0.0) u += 1.0;
  }
  #pragma unroll
  for (int off = 32; off; off >>= 1) {
    e += __shfl_xor(e, off, 64);
    u += __shfl_xor(u, off, 64);
  }
  if (lane == 0) { she[w] = e; shu[w] = u; }
  __syncthreads();
  if (threadIdx.x == 0) {
    double E = she[0] + she[1] + she[2] + she[3];
    double U = shu[0] + shu[1] + shu[2] + shu[3];
    ent[b] = E; perp[b] = exp(E); uniq[b] = U;
  }
}

// ---------------- finalize scalars ----------------
__global__ void final_kernel(const double* __restrict__ sse,
                             const double* __restrict__ perp,
                             const double* __restrict__ ent,
                             const double* __restrict__ uniq,
                             float* __restrict__ out, int N) {
  if (threadIdx.x == 0 && blockIdx.x == 0) {
    double mp = 0.0, me = 0.0, mu = 0.0;
    for (int b = 0; b < NBATCH; ++b) { mp += perp[b]; me += ent[b]; mu += uniq[b]; }
    mp /= NBATCH; me /= NBATCH; mu /= NBATCH;
    double loss = *sse / ((double)N * (double)D64);
    size_t voff = (size_t)N * D64;
    size_t coff = voff + 1;
    size_t poff = coff + 1 + (size_t)N;
    out[voff] = (float)loss;
    out[coff] = (float)loss;
    out[poff] = (float)mp;
    out[poff + 1] = (float)me;
    out[poff + 2] = (float)mu;
  }
}

extern "C" void kernel_launch(void* const* d_in, const int* in_sizes, int n_in,
                              void* d_out, int out_size, void* d_ws, size_t ws_size,
                              hipStream_t stream) {
  const float* z = (const float*)d_in[0];
  const int* bid = (const int*)d_in[1];
  const float* cb = (const float*)d_in[2];
  int N = in_sizes[1];
  int Dd = in_sizes[0] / N;
  int K = in_sizes[2] / Dd;
  float* out = (float*)d_out;

  // workspace layout (256B-aligned chunks)
  char* ws = (char*)d_ws;
  size_t off = 0;
  auto alloc = [&](size_t bytes) {
    void* p = ws + off;
    off += (bytes + 255) & ~(size_t)255;
    return p;
  };
  unsigned int* counts = (unsigned int*)alloc((size_t)NBATCH * K * 4);
  double* sse  = (double*)alloc(8);
  double* perp = (double*)alloc(8 * NBATCH);
  double* ent  = (double*)alloc(8 * NBATCH);
  double* uniq = (double*)alloc(8 * NBATCH);
  float* csq = (float*)alloc((size_t)K * 4);
  short* cbh = (short*)alloc((size_t)K * D64 * 2);
  float* bm = (float*)alloc((size_t)N * NCHUNK * 4);

  size_t ioff = (size_t)N * Dd + 2;

  csq_cvt_kernel<<<(K * 64 + 255) / 256, 256, 0, stream>>>(
      cb, csq, cbh, counts, sse, K);
  chunkmin_kernel<<<N / 128, 256, 0, stream>>>(z, cbh, csq, bm, N, K);
  rescore_quant_kernel<<<N / 256, 256, 0, stream>>>(
      z, cb, csq, bm, bid, out + ioff, out, counts, sse, N, K);
  stats_kernel<<<NBATCH, 256, 0, stream>>>(counts, perp, ent, uniq, K);
  final_kernel<<<1, 64, 0, stream>>>(sse, perp, ent, uniq, out, N);
}

// Round 11
// 1550.670 us; speedup vs baseline: 2.3469x; 2.3469x over previous
//
#include <hip/hip_runtime.h>
#include <math.h>

#define D64 64
#define NBATCH 8
#define CBAND 2.0f
#define CHUNK 128                 // codes per LDS chunk (16 KB)
#define NCHUNK 64                 // K / CHUNK
#define CG 32                     // candidate granularity (codes per bm group)
#define NGRP 256                  // K / CG

typedef short s16x8 __attribute__((ext_vector_type(8)));   // 8 bf16 (bit pattern)
typedef float f32x4 __attribute__((ext_vector_type(4)));

#define GLOAD16(g, l) __builtin_amdgcn_global_load_lds( \
    (const __attribute__((address_space(1))) unsigned*)(g), \
    (__attribute__((address_space(3))) unsigned*)(l), 16, 0, 0)
#define GLOAD4(g, l) __builtin_amdgcn_global_load_lds( \
    (const __attribute__((address_space(1))) unsigned*)(g), \
    (__attribute__((address_space(3))) unsigned*)(l), 4, 0, 0)

__device__ inline unsigned short f2bf(float f) {
  unsigned u = __builtin_bit_cast(unsigned, f);
  unsigned r = (u + 0x7FFFu + ((u >> 16) & 1u)) >> 16;
  return (unsigned short)r;
}
__device__ inline float bflo(unsigned u) {      // low u16 -> f32
  return __builtin_bit_cast(float, (u & 0xFFFFu) << 16);
}
__device__ inline float bfhi(unsigned u) {      // high u16 -> f32
  return __builtin_bit_cast(float, u & 0xFFFF0000u);
}

// ---------------- c_sq + bf16 convert + workspace zeroing ----------------
__global__ __launch_bounds__(256) void csq_cvt_kernel(
    const float* __restrict__ cb, float* __restrict__ csq,
    short* __restrict__ cbh,
    unsigned int* __restrict__ counts, double* __restrict__ sse, int K) {
  int t = blockIdx.x * blockDim.x + threadIdx.x;
  if (t < NBATCH * K) counts[t] = 0u;
  if (t == 0) *sse = 0.0;
  int row = t >> 6, lane = t & 63;
  if (row >= K) return;
  float v = cb[(size_t)row * D64 + lane];
  cbh[(size_t)row * D64 + lane] = (short)f2bf(v);
  v *= v;
  #pragma unroll
  for (int off = 32; off; off >>= 1) v += __shfl_xor(v, off, 64);
  if (lane == 0) csq[row] = v;
}

// -------- single sweep: per-(point, 32-code group) bf16-score min --------
// SWAPPED MFMA operands: A = codes (rows), B = z (cols).
// acc layout: col = lane&15 -> point, row = (lane>>4)*4 + reg -> code.
// Per-lane LDS/global load patterns identical to the validated kernels.
// block = 4 waves x 32 points = 128 points, full K, LDS-staged codebook.
__global__ __launch_bounds__(256, 2) void sweep_kernel(
    const float* __restrict__ z, const short* __restrict__ cbh,
    const float* __restrict__ csq,
    unsigned short* __restrict__ bm, float* __restrict__ pmin, int N, int K) {
  __shared__ short lcb[2][CHUNK * D64];     // 2 x 16 KB
  __shared__ float lcsq[2][CHUNK];          // 2 x 512 B

  int w = threadIdx.x >> 6;
  int l = threadIdx.x & 63;
  int lr = l & 15, lg = l >> 4;
  int base = blockIdx.x * 128 + w * 32;

  // ---- Z fragments (B operand): z[point = base+pt*16+lr][dims lg*8 + j] ----
  s16x8 Z[2][2];
  #pragma unroll
  for (int pt = 0; pt < 2; ++pt) {
    int row = base + pt * 16 + lr;
    #pragma unroll
    for (int kh = 0; kh < 2; ++kh) {
      const float4* zp = reinterpret_cast<const float4*>(
          z + (size_t)row * D64 + kh * 32 + lg * 8);
      float4 p0 = zp[0], p1 = zp[1];
      s16x8 t;
      t[0] = (short)f2bf(p0.x); t[1] = (short)f2bf(p0.y);
      t[2] = (short)f2bf(p0.z); t[3] = (short)f2bf(p0.w);
      t[4] = (short)f2bf(p1.x); t[5] = (short)f2bf(p1.y);
      t[6] = (short)f2bf(p1.z); t[7] = (short)f2bf(p1.w);
      Z[pt][kh] = t;
    }
  }

  // per-lane swizzled LDS read offsets for the code (A) fragments
  int sw = (lr & 7) << 4;
  int p0off = ((lr * 128 + lg * 16) ^ sw);
  int p1off = ((lr * 128 + 64 + lg * 16) ^ sw);
  int swl = (l >> 3) << 4;                  // staging source swizzle

  const char* cbbytes = (const char*)cbh;
#define STAGE(chunk, b)                                                       \
  {                                                                           \
    const char* src = cbbytes + (size_t)(chunk) * (CHUNK * 128);              \
    char* dstb = (char*)lcb[b];                                               \
    _Pragma("unroll")                                                         \
    for (int j = 0; j < 4; ++j) {                                             \
      int X = (w * 4 + j) * 1024 + l * 16;                                    \
      GLOAD16(src + (X ^ swl), dstb + (w * 4 + j) * 1024);                    \
    }                                                                         \
    const char* csrc = (const char*)(csq + (chunk) * CHUNK) + (w & 1) * 256;  \
    GLOAD4(csrc + l * 4, (char*)lcsq[b] + (w & 1) * 256);                     \
  }

  float gm0 = INFINITY, gm1 = INFINITY;     // exact fp32 running min per point

  // compute chunk c out of buffer b
  auto do_chunk = [&](int c, int b) {
    const char* pb0 = (const char*)lcb[b] + p0off;
    const char* pb1 = (const char*)lcb[b] + p1off;
    unsigned pk0[2] = {0u, 0u};             // pt0: 4 bf16 group-mins packed
    unsigned pk1[2] = {0u, 0u};             // pt1
    float mprev0 = 0.f, mprev1 = 0.f;
    #pragma unroll
    for (int i = 0; i < 8; ++i) {
      s16x8 CA0 = *(const s16x8*)(pb0 + i * 2048);   // codes i*16+(lg*4+r), dims 0-31
      s16x8 CA1 = *(const s16x8*)(pb1 + i * 2048);   // dims 32-63
      float4 cqv = *(const float4*)(lcsq[b] + i * 16 + lg * 4);
      float m16[2];
      #pragma unroll
      for (int pt = 0; pt < 2; ++pt) {
        f32x4 acc = {0.f, 0.f, 0.f, 0.f};
        acc = __builtin_amdgcn_mfma_f32_16x16x32_bf16(CA0, Z[pt][0], acc, 0, 0, 0);
        acc = __builtin_amdgcn_mfma_f32_16x16x32_bf16(CA1, Z[pt][1], acc, 0, 0, 0);
        float s0 = fmaf(-2.0f, acc[0], cqv.x);
        float s1 = fmaf(-2.0f, acc[1], cqv.y);
        float s2 = fmaf(-2.0f, acc[2], cqv.z);
        float s3 = fmaf(-2.0f, acc[3], cqv.w);
        float m = fminf(fminf(s0, s1), fminf(s2, s3));  // min over 4 reg-codes
        m = fminf(m, __shfl_xor(m, 16, 64));            // min over lane-group codes
        m = fminf(m, __shfl_xor(m, 32, 64));
        m16[pt] = m;
      }
      if (i & 1) {
        float m32a = fminf(mprev0, m16[0]);
        float m32b = fminf(mprev1, m16[1]);
        gm0 = fminf(gm0, m32a);
        gm1 = fminf(gm1, m32b);
        int word = i >> 2, shft = ((i >> 1) & 1) * 16;
        pk0[word] |= ((unsigned)f2bf(m32a)) << shft;
        pk1[word] |= ((unsigned)f2bf(m32b)) << shft;
      } else {
        mprev0 = m16[0];
        mprev1 = m16[1];
      }
    }
    if (l < 16) {
      // bm[n][NGRP] ushort row-major; chunk c covers groups c*4..c*4+3
      unsigned short* r0 = bm + (size_t)(base + l) * NGRP + c * 4;
      unsigned short* r1 = bm + (size_t)(base + 16 + l) * NGRP + c * 4;
      *reinterpret_cast<uint2*>(r0) = make_uint2(pk0[0], pk0[1]);
      *reinterpret_cast<uint2*>(r1) = make_uint2(pk1[0], pk1[1]);
    }
  };

  STAGE(0, 0);
  __syncthreads();
  for (int c = 0; c < NCHUNK; ++c) {
    if (c + 1 < NCHUNK) STAGE(c + 1, (c + 1) & 1);
    do_chunk(c, c & 1);
    __syncthreads();
  }
  if (l < 16) {
    pmin[base + l] = gm0;
    pmin[base + 16 + l] = gm1;
  }
#undef STAGE
}

// ---- exact fp32 rescan of qualifying 32-code groups + fp64 tiebreak ----
__global__ __launch_bounds__(256) void rescore_quant_kernel(
    const float* __restrict__ z, const float* __restrict__ cb,
    const float* __restrict__ csq, const unsigned short* __restrict__ bm,
    const float* __restrict__ pmin, const int* __restrict__ batch_raw,
    float* __restrict__ out_idx, float* __restrict__ outq,
    unsigned int* __restrict__ counts, double* __restrict__ sse,
    int N, int K) {
  __shared__ double red[4];
  int n = blockIdx.x * blockDim.x + threadIdx.x;

  const float4* z4 = reinterpret_cast<const float4*>(z) + (size_t)n * 16;
  float4 zr[16];
  #pragma unroll
  for (int d = 0; d < 16; ++d) zr[d] = z4[d];

  float thr = pmin[n] + CBAND;

  float b1 = INFINITY, b2 = INFINITY;
  int i1 = 0x7FFFFFFF, i2 = 0x7FFFFFFF;

  const uint4* bmv = reinterpret_cast<const uint4*>(bm + (size_t)n * NGRP);
  for (int t = 0; t < NGRP / 8; ++t) {      // 8 groups per uint4
    uint4 u = bmv[t];
    float v0 = bflo(u.x), v1 = bfhi(u.x), v2 = bflo(u.y), v3 = bfhi(u.y);
    float v4 = bflo(u.z), v5 = bfhi(u.z), v6 = bflo(u.w), v7 = bfhi(u.w);
    float m8 = fminf(fminf(fminf(v0, v1), fminf(v2, v3)),
                     fminf(fminf(v4, v5), fminf(v6, v7)));
    if (m8 > thr) continue;
    float vv[8] = {v0, v1, v2, v3, v4, v5, v6, v7};
    #pragma unroll
    for (int j = 0; j < 8; ++j) {
      if (vv[j] <= thr) {
        int k0 = (t * 8 + j) * CG;
        for (int kk = 0; kk < CG; kk += 2) {
          int ka = k0 + kk;
          const float4* c0 = reinterpret_cast<const float4*>(cb) + (size_t)ka * 16;
          const float4* c1 = c0 + 16;
          float4 a0 = {0.f, 0.f, 0.f, 0.f}, a1 = {0.f, 0.f, 0.f, 0.f};
          #pragma unroll
          for (int d = 0; d < 16; ++d) {
            float4 q0 = c0[d], q1 = c1[d], zz = zr[d];
            a0.x = fmaf(q0.x, zz.x, a0.x);
            a0.y = fmaf(q0.y, zz.y, a0.y);
            a0.z = fmaf(q0.z, zz.z, a0.z);
            a0.w = fmaf(q0.w, zz.w, a0.w);
            a1.x = fmaf(q1.x, zz.x, a1.x);
            a1.y = fmaf(q1.y, zz.y, a1.y);
            a1.z = fmaf(q1.z, zz.z, a1.z);
            a1.w = fmaf(q1.w, zz.w, a1.w);
          }
          float s0 = csq[ka]     - 2.0f * ((a0.x + a0.y) + (a0.z + a0.w));
          float s1 = csq[ka + 1] - 2.0f * ((a1.x + a1.y) + (a1.z + a1.w));
          // top-2, strict < keeps lowest index on exact ties (ascending k)
          bool lt1 = s0 < b1;
          float cand = lt1 ? b1 : s0; int ci = lt1 ? i1 : ka;
          b1 = lt1 ? s0 : b1;  i1 = lt1 ? ka : i1;
          bool lt2 = cand < b2;
          b2 = lt2 ? cand : b2; i2 = lt2 ? ci : i2;
          lt1 = s1 < b1;
          cand = lt1 ? b1 : s1; ci = lt1 ? i1 : (ka + 1);
          b1 = lt1 ? s1 : b1;  i1 = lt1 ? (ka + 1) : i1;
          lt2 = cand < b2;
          b2 = lt2 ? cand : b2; i2 = lt2 ? ci : i2;
        }
      }
    }
  }

  int final_i = i1;
  if (i2 != 0x7FFFFFFF && (b2 - b1) < 1e-3f) {
    const float* zp  = z  + (size_t)n  * D64;
    const float* c1p = cb + (size_t)i1 * D64;
    const float* c2p = cb + (size_t)i2 * D64;
    double d0 = 0.0, d1 = 0.0;
    for (int d = 0; d < D64; ++d) {
      double t0 = (double)zp[d] - (double)c1p[d];
      double t1 = (double)zp[d] - (double)c2p[d];
      d0 += t0 * t0;
      d1 += t1 * t1;
    }
    if (d1 < d0 || (d1 == d0 && i2 < i1)) final_i = i2;
  }

  out_idx[n] = (float)final_i;

  int is64 = (batch_raw[N - 1] == 0) ? 1 : 0;
  int b = is64 ? batch_raw[2 * n] : batch_raw[n];
  atomicAdd(&counts[(size_t)b * K + final_i], 1u);

  // ---- quantize + straight-through + SSE (z row already in registers) ----
  const float4* cr = reinterpret_cast<const float4*>(cb) + (size_t)final_i * 16;
  float4* oq = reinterpret_cast<float4*>(outq) + (size_t)n * 16;
  double local = 0.0;
  #pragma unroll
  for (int d = 0; d < 16; ++d) {
    float4 q = cr[d], zz = zr[d];
    float4 t = {q.x - zz.x, q.y - zz.y, q.z - zz.z, q.w - zz.w};
    float4 st = {zz.x + t.x, zz.y + t.y, zz.z + t.z, zz.w + t.w};
    oq[d] = st;
    local += (double)t.x * t.x + (double)t.y * t.y +
             (double)t.z * t.z + (double)t.w * t.w;
  }
  #pragma unroll
  for (int off = 32; off; off >>= 1) local += __shfl_xor(local, off, 64);
  int lane = threadIdx.x & 63, wv = threadIdx.x >> 6;
  if (lane == 0) red[wv] = local;
  __syncthreads();
  if (threadIdx.x == 0) atomicAdd(sse, red[0] + red[1] + red[2] + red[3]);
}

// ---------------- per-batch entropy / perplexity / unique ----------------
__global__ __launch_bounds__(256) void stats_kernel(
    const unsigned int* __restrict__ counts,
    double* __restrict__ perp, double* __restrict__ ent,
    double* __restrict__ uniq, int K) {
  __shared__ double sh4[4], she[4], shu[4];
  int b = blockIdx.x;
  const unsigned int* c = counts + (size_t)b * K;
  int lane = threadIdx.x & 63, w = threadIdx.x >> 6;

  double tot = 0.0;
  for (int k = threadIdx.x; k < K; k += blockDim.x) tot += (double)c[k];
  #pragma unroll
  for (int off = 32; off; off >>= 1) tot += __shfl_xor(tot, off, 64);
  if (lane == 0) sh4[w] = tot;
  __syncthreads();
  double total = sh4[0] + sh4[1] + sh4[2] + sh4[3];
  double denom = fmax(total, 1.0);

  double e = 0.0, u = 0.0;
  for (int k = threadIdx.x; k < K; k += blockDim.x) {
    double cc = (double)c[k];
    double p = cc / denom;
    e -= p * log(p + 1e-10);
    if (cc > 0.0) u += 1.0;
  }
  #pragma unroll
  for (int off = 32; off; off >>= 1) {
    e += __shfl_xor(e, off, 64);
    u += __shfl_xor(u, off, 64);
  }
  if (lane == 0) { she[w] = e; shu[w] = u; }
  __syncthreads();
  if (threadIdx.x == 0) {
    double E = she[0] + she[1] + she[2] + she[3];
    double U = shu[0] + shu[1] + shu[2] + shu[3];
    ent[b] = E; perp[b] = exp(E); uniq[b] = U;
  }
}

// ---------------- finalize scalars ----------------
__global__ void final_kernel(const double* __restrict__ sse,
                             const double* __restrict__ perp,
                             const double* __restrict__ ent,
                             const double* __restrict__ uniq,
                             float* __restrict__ out, int N) {
  if (threadIdx.x == 0 && blockIdx.x == 0) {
    double mp = 0.0, me = 0.0, mu = 0.0;
    for (int b = 0; b < NBATCH; ++b) { mp += perp[b]; me += ent[b]; mu += uniq[b]; }
    mp /= NBATCH; me /= NBATCH; mu /= NBATCH;
    double loss = *sse / ((double)N * (double)D64);
    size_t voff = (size_t)N * D64;
    size_t coff = voff + 1;
    size_t poff = coff + 1 + (size_t)N;
    out[voff] = (float)loss;
    out[coff] = (float)loss;
    out[poff] = (float)mp;
    out[poff + 1] = (float)me;
    out[poff + 2] = (float)mu;
  }
}

extern "C" void kernel_launch(void* const* d_in, const int* in_sizes, int n_in,
                              void* d_out, int out_size, void* d_ws, size_t ws_size,
                              hipStream_t stream) {
  const float* z = (const float*)d_in[0];
  const int* bid = (const int*)d_in[1];
  const float* cb = (const float*)d_in[2];
  int N = in_sizes[1];
  int Dd = in_sizes[0] / N;
  int K = in_sizes[2] / Dd;
  float* out = (float*)d_out;

  // workspace layout (256B-aligned chunks); total ~34 MB
  char* ws = (char*)d_ws;
  size_t off = 0;
  auto alloc = [&](size_t bytes) {
    void* p = ws + off;
    off += (bytes + 255) & ~(size_t)255;
    return p;
  };
  unsigned int* counts = (unsigned int*)alloc((size_t)NBATCH * K * 4);
  double* sse  = (double*)alloc(8);
  double* perp = (double*)alloc(8 * NBATCH);
  double* ent  = (double*)alloc(8 * NBATCH);
  double* uniq = (double*)alloc(8 * NBATCH);
  float* csq = (float*)alloc((size_t)K * 4);
  short* cbh = (short*)alloc((size_t)K * D64 * 2);
  float* pmin = (float*)alloc((size_t)N * 4);
  unsigned short* bm = (unsigned short*)alloc((size_t)N * NGRP * 2);

  size_t ioff = (size_t)N * Dd + 2;

  csq_cvt_kernel<<<(K * 64 + 255) / 256, 256, 0, stream>>>(
      cb, csq, cbh, counts, sse, K);
  sweep_kernel<<<N / 128, 256, 0, stream>>>(z, cbh, csq, bm, pmin, N, K);
  rescore_quant_kernel<<<N / 256, 256, 0, stream>>>(
      z, cb, csq, bm, pmin, bid, out + ioff, out, counts, sse, N, K);
  stats_kernel<<<NBATCH, 256, 0, stream>>>(counts, perp, ent, uniq, K);
  final_kernel<<<1, 64, 0, stream>>>(sse, perp, ent, uniq, out, N);
}

// Round 12
// 345.667 us; speedup vs baseline: 10.5284x; 4.4860x over previous
//
#include <hip/hip_runtime.h>
#include <math.h>

#define D64 64
#define NBATCH 8
#define CBAND 2.0f
#define CHUNK 128                 // codes per LDS chunk (16 KB)
#define NCHUNK 64                 // K / CHUNK
#define CG 32                     // candidate granularity (codes per bm group)
#define NGRP 256                  // K / CG
#define MAXG 16                   // max qualifying groups per point

typedef short s16x8 __attribute__((ext_vector_type(8)));   // 8 bf16 (bit pattern)
typedef float f32x4 __attribute__((ext_vector_type(4)));

#define GLOAD16(g, l) __builtin_amdgcn_global_load_lds( \
    (const __attribute__((address_space(1))) unsigned*)(g), \
    (__attribute__((address_space(3))) unsigned*)(l), 16, 0, 0)
#define GLOAD4(g, l) __builtin_amdgcn_global_load_lds( \
    (const __attribute__((address_space(1))) unsigned*)(g), \
    (__attribute__((address_space(3))) unsigned*)(l), 4, 0, 0)

__device__ inline unsigned short f2bf(float f) {
  unsigned u = __builtin_bit_cast(unsigned, f);
  unsigned r = (u + 0x7FFFu + ((u >> 16) & 1u)) >> 16;
  return (unsigned short)r;
}
__device__ inline float bflo(unsigned u) {      // low u16 -> f32
  return __builtin_bit_cast(float, (u & 0xFFFFu) << 16);
}
__device__ inline float bfhi(unsigned u) {      // high u16 -> f32
  return __builtin_bit_cast(float, u & 0xFFFF0000u);
}

// ---------------- c_sq + bf16 convert + workspace zeroing ----------------
__global__ __launch_bounds__(256) void csq_cvt_kernel(
    const float* __restrict__ cb, float* __restrict__ csq,
    short* __restrict__ cbh,
    unsigned int* __restrict__ counts, double* __restrict__ sse_parts, int K) {
  int t = blockIdx.x * blockDim.x + threadIdx.x;
  if (t < NBATCH * K) counts[t] = 0u;
  if (t < 64) sse_parts[t] = 0.0;
  int row = t >> 6, lane = t & 63;
  if (row >= K) return;
  float v = cb[(size_t)row * D64 + lane];
  cbh[(size_t)row * D64 + lane] = (short)f2bf(v);
  v *= v;
  #pragma unroll
  for (int off = 32; off; off >>= 1) v += __shfl_xor(v, off, 64);
  if (lane == 0) csq[row] = v;
}

// -------- single sweep: per-(point, 32-code group) bf16-score min --------
// SWAPPED MFMA operands: A = codes (rows), B = z (cols).
// acc layout: col = lane&15 -> point, row = (lane>>4)*4 + reg -> code.
// block = 4 waves x 32 points = 128 points, full K, LDS-staged codebook.
__global__ __launch_bounds__(256, 2) void sweep_kernel(
    const float* __restrict__ z, const short* __restrict__ cbh,
    const float* __restrict__ csq,
    unsigned short* __restrict__ bm, float* __restrict__ pmin, int N, int K) {
  __shared__ short lcb[2][CHUNK * D64];     // 2 x 16 KB
  __shared__ float lcsq[2][CHUNK];          // 2 x 512 B

  int w = threadIdx.x >> 6;
  int l = threadIdx.x & 63;
  int lr = l & 15, lg = l >> 4;
  int base = blockIdx.x * 128 + w * 32;

  // ---- Z fragments (B operand): z[point = base+pt*16+lr][dims lg*8 + j] ----
  s16x8 Z[2][2];
  #pragma unroll
  for (int pt = 0; pt < 2; ++pt) {
    int row = base + pt * 16 + lr;
    #pragma unroll
    for (int kh = 0; kh < 2; ++kh) {
      const float4* zp = reinterpret_cast<const float4*>(
          z + (size_t)row * D64 + kh * 32 + lg * 8);
      float4 p0 = zp[0], p1 = zp[1];
      s16x8 t;
      t[0] = (short)f2bf(p0.x); t[1] = (short)f2bf(p0.y);
      t[2] = (short)f2bf(p0.z); t[3] = (short)f2bf(p0.w);
      t[4] = (short)f2bf(p1.x); t[5] = (short)f2bf(p1.y);
      t[6] = (short)f2bf(p1.z); t[7] = (short)f2bf(p1.w);
      Z[pt][kh] = t;
    }
  }

  // per-lane swizzled LDS read offsets for the code (A) fragments
  int sw = (lr & 7) << 4;
  int p0off = ((lr * 128 + lg * 16) ^ sw);
  int p1off = ((lr * 128 + 64 + lg * 16) ^ sw);
  int swl = (l >> 3) << 4;                  // staging source swizzle

  const char* cbbytes = (const char*)cbh;
#define STAGE(chunk, b)                                                       \
  {                                                                           \
    const char* src = cbbytes + (size_t)(chunk) * (CHUNK * 128);              \
    char* dstb = (char*)lcb[b];                                               \
    _Pragma("unroll")                                                         \
    for (int j = 0; j < 4; ++j) {                                             \
      int X = (w * 4 + j) * 1024 + l * 16;                                    \
      GLOAD16(src + (X ^ swl), dstb + (w * 4 + j) * 1024);                    \
    }                                                                         \
    const char* csrc = (const char*)(csq + (chunk) * CHUNK) + (w & 1) * 256;  \
    GLOAD4(csrc + l * 4, (char*)lcsq[b] + (w & 1) * 256);                     \
  }

  float gm0 = INFINITY, gm1 = INFINITY;     // exact fp32 running min per point

  auto do_chunk = [&](int c, int b) {
    const char* pb0 = (const char*)lcb[b] + p0off;
    const char* pb1 = (const char*)lcb[b] + p1off;
    unsigned pk0[2] = {0u, 0u};             // pt0: 4 bf16 group-mins packed
    unsigned pk1[2] = {0u, 0u};             // pt1
    float mprev0 = 0.f, mprev1 = 0.f;
    #pragma unroll
    for (int i = 0; i < 8; ++i) {
      s16x8 CA0 = *(const s16x8*)(pb0 + i * 2048);   // codes i*16+(lg*4+r), dims 0-31
      s16x8 CA1 = *(const s16x8*)(pb1 + i * 2048);   // dims 32-63
      float4 cqv = *(const float4*)(lcsq[b] + i * 16 + lg * 4);
      float m16[2];
      #pragma unroll
      for (int pt = 0; pt < 2; ++pt) {
        f32x4 acc = {0.f, 0.f, 0.f, 0.f};
        acc = __builtin_amdgcn_mfma_f32_16x16x32_bf16(CA0, Z[pt][0], acc, 0, 0, 0);
        acc = __builtin_amdgcn_mfma_f32_16x16x32_bf16(CA1, Z[pt][1], acc, 0, 0, 0);
        float s0 = fmaf(-2.0f, acc[0], cqv.x);
        float s1 = fmaf(-2.0f, acc[1], cqv.y);
        float s2 = fmaf(-2.0f, acc[2], cqv.z);
        float s3 = fmaf(-2.0f, acc[3], cqv.w);
        float m = fminf(fminf(s0, s1), fminf(s2, s3));  // min over 4 reg-codes
        m = fminf(m, __shfl_xor(m, 16, 64));            // min over lane-group codes
        m = fminf(m, __shfl_xor(m, 32, 64));
        m16[pt] = m;
      }
      if (i & 1) {
        float m32a = fminf(mprev0, m16[0]);
        float m32b = fminf(mprev1, m16[1]);
        gm0 = fminf(gm0, m32a);
        gm1 = fminf(gm1, m32b);
        int word = i >> 2, shft = ((i >> 1) & 1) * 16;
        pk0[word] |= ((unsigned)f2bf(m32a)) << shft;
        pk1[word] |= ((unsigned)f2bf(m32b)) << shft;
      } else {
        mprev0 = m16[0];
        mprev1 = m16[1];
      }
    }
    if (l < 16) {
      unsigned short* r0 = bm + (size_t)(base + l) * NGRP + c * 4;
      unsigned short* r1 = bm + (size_t)(base + 16 + l) * NGRP + c * 4;
      *reinterpret_cast<uint2*>(r0) = make_uint2(pk0[0], pk0[1]);
      *reinterpret_cast<uint2*>(r1) = make_uint2(pk1[0], pk1[1]);
    }
  };

  STAGE(0, 0);
  __syncthreads();
  for (int c = 0; c < NCHUNK; ++c) {
    if (c + 1 < NCHUNK) STAGE(c + 1, (c + 1) & 1);
    do_chunk(c, c & 1);
    __syncthreads();
  }
  if (l < 16) {
    pmin[base + l] = gm0;
    pmin[base + 16 + l] = gm1;
  }
#undef STAGE
}

// ---- wave-per-point exact fp32 rescore + fp64 tiebreak + outputs ----
__global__ __launch_bounds__(256) void rescore_wave_kernel(
    const float* __restrict__ z, const float* __restrict__ cb,
    const float* __restrict__ csq, const unsigned short* __restrict__ bm,
    const float* __restrict__ pmin, const int* __restrict__ batch_raw,
    float* __restrict__ out_idx, float* __restrict__ outq,
    unsigned int* __restrict__ counts, double* __restrict__ sse_parts,
    int N, int K) {
  __shared__ int glist[4][MAXG];
  __shared__ int gcnt[4];
  __shared__ double red[4];
  int w = threadIdx.x >> 6, l = threadIdx.x & 63;
  int n = blockIdx.x * 4 + w;

  if (l == 0) gcnt[w] = 0;
  __syncthreads();

  float thr = pmin[n] + CBAND;
  // bm row: lane l covers groups 4l..4l+3 (coalesced uint2)
  uint2 u = reinterpret_cast<const uint2*>(bm + (size_t)n * NGRP)[l];
  float v0 = bflo(u.x), v1 = bfhi(u.x), v2 = bflo(u.y), v3 = bfhi(u.y);
  if (v0 <= thr) { int o = atomicAdd(&gcnt[w], 1); if (o < MAXG) glist[w][o] = l * 4 + 0; }
  if (v1 <= thr) { int o = atomicAdd(&gcnt[w], 1); if (o < MAXG) glist[w][o] = l * 4 + 1; }
  if (v2 <= thr) { int o = atomicAdd(&gcnt[w], 1); if (o < MAXG) glist[w][o] = l * 4 + 2; }
  if (v3 <= thr) { int o = atomicAdd(&gcnt[w], 1); if (o < MAXG) glist[w][o] = l * 4 + 3; }
  __syncthreads();
  int ng = min(gcnt[w], MAXG);
  int ncand = ng * CG;

  // z row in registers (same values in every lane; broadcast loads)
  const float4* z4 = reinterpret_cast<const float4*>(z) + (size_t)n * 16;
  float4 zr[16];
  #pragma unroll
  for (int d = 0; d < 16; ++d) zr[d] = z4[d];

  float b1 = INFINITY, b2 = INFINITY;
  int i1 = 0x7FFFFFFF, i2 = 0x7FFFFFFF;
  for (int c0 = 0; c0 < ncand; c0 += 64) {
    int idx = c0 + l;
    bool act = idx < ncand;
    int k = act ? (glist[w][idx >> 5] * CG + (idx & 31)) : 0;
    float s = INFINITY;
    if (act) {
      const float4* cr = reinterpret_cast<const float4*>(cb) + (size_t)k * 16;
      float4 a = {0.f, 0.f, 0.f, 0.f};
      #pragma unroll
      for (int d = 0; d < 16; ++d) {
        float4 q = cr[d], zz = zr[d];
        a.x = fmaf(q.x, zz.x, a.x);
        a.y = fmaf(q.y, zz.y, a.y);
        a.z = fmaf(q.z, zz.z, a.z);
        a.w = fmaf(q.w, zz.w, a.w);
      }
      s = csq[k] - 2.0f * ((a.x + a.y) + (a.z + a.w));
    }
    int kk = act ? k : 0x7FFFFFFF;
    // lex (score, index) insert — same comparator as validated sequential
    bool bet1 = (s < b1) || (s == b1 && kk < i1);
    float cs = bet1 ? b1 : s;  int ci = bet1 ? i1 : kk;
    b1 = bet1 ? s : b1;        i1 = bet1 ? kk : i1;
    bool bet2 = (cs < b2) || (cs == b2 && ci < i2);
    b2 = bet2 ? cs : b2;       i2 = bet2 ? ci : i2;
  }
  // butterfly merge of per-lane top-2 (lex order)
  #pragma unroll
  for (int off = 1; off < 64; off <<= 1) {
    float o1 = __shfl_xor(b1, off, 64); int j1 = __shfl_xor(i1, off, 64);
    float o2 = __shfl_xor(b2, off, 64); int j2 = __shfl_xor(i2, off, 64);
    bool t1 = (o1 < b1) || (o1 == b1 && j1 < i1);
    float cs = t1 ? b1 : o1;  int ci = t1 ? i1 : j1;
    b1 = t1 ? o1 : b1;        i1 = t1 ? j1 : i1;
    bool t2 = (cs < b2) || (cs == b2 && ci < i2);
    b2 = t2 ? cs : b2;        i2 = t2 ? ci : i2;
    // o2 >=lex o1 >=lex new b1, so o2 can only displace b2
    bool t3 = (o2 < b2) || (o2 == b2 && j2 < i2);
    b2 = t3 ? o2 : b2;        i2 = t3 ? j2 : i2;
  }

  int final_i = i1;
  if (i2 != 0x7FFFFFFF && (b2 - b1) < 1e-3f) {
    // fp64 rescore, wave-parallel over dims (branch is wave-uniform)
    double zd = (double)z[(size_t)n * D64 + l];
    double t0 = zd - (double)cb[(size_t)i1 * D64 + l];
    double t1 = zd - (double)cb[(size_t)i2 * D64 + l];
    double d0 = t0 * t0, d1 = t1 * t1;
    #pragma unroll
    for (int off = 1; off < 64; off <<= 1) {
      d0 += __shfl_xor(d0, off, 64);
      d1 += __shfl_xor(d1, off, 64);
    }
    if (d1 < d0 || (d1 == d0 && i2 < i1)) final_i = i2;
  }

  // ---- outputs: quantize + straight-through + SSE (lane-per-dim) ----
  float zl = z[(size_t)n * D64 + l];
  float ql = cb[(size_t)final_i * D64 + l];
  float tl = ql - zl;
  outq[(size_t)n * D64 + l] = zl + tl;
  double loc = (double)tl * tl;
  #pragma unroll
  for (int off = 1; off < 64; off <<= 1) loc += __shfl_xor(loc, off, 64);
  if (l == 0) {
    out_idx[n] = (float)final_i;
    int is64 = (batch_raw[N - 1] == 0) ? 1 : 0;
    int b = is64 ? batch_raw[2 * n] : batch_raw[n];
    atomicAdd(&counts[(size_t)b * K + final_i], 1u);
    red[w] = loc;
  }
  __syncthreads();
  if (threadIdx.x == 0)
    atomicAdd(&sse_parts[blockIdx.x & 63], red[0] + red[1] + red[2] + red[3]);
}

// ---------------- per-batch entropy / perplexity / unique ----------------
__global__ __launch_bounds__(256) void stats_kernel(
    const unsigned int* __restrict__ counts,
    double* __restrict__ perp, double* __restrict__ ent,
    double* __restrict__ uniq, int K) {
  __shared__ double sh4[4], she[4], shu[4];
  int b = blockIdx.x;
  const unsigned int* c = counts + (size_t)b * K;
  int lane = threadIdx.x & 63, w = threadIdx.x >> 6;

  double tot = 0.0;
  for (int k = threadIdx.x; k < K; k += blockDim.x) tot += (double)c[k];
  #pragma unroll
  for (int off = 32; off; off >>= 1) tot += __shfl_xor(tot, off, 64);
  if (lane == 0) sh4[w] = tot;
  __syncthreads();
  double total = sh4[0] + sh4[1] + sh4[2] + sh4[3];
  double denom = fmax(total, 1.0);

  double e = 0.0, u = 0.0;
  for (int k = threadIdx.x; k < K; k += blockDim.x) {
    double cc = (double)c[k];
    double p = cc / denom;
    e -= p * log(p + 1e-10);
    if (cc > 0.0) u += 1.0;
  }
  #pragma unroll
  for (int off = 32; off; off >>= 1) {
    e += __shfl_xor(e, off, 64);
    u += __shfl_xor(u, off, 64);
  }
  if (lane == 0) { she[w] = e; shu[w] = u; }
  __syncthreads();
  if (threadIdx.x == 0) {
    double E = she[0] + she[1] + she[2] + she[3];
    double U = shu[0] + shu[1] + shu[2] + shu[3];
    ent[b] = E; perp[b] = exp(E); uniq[b] = U;
  }
}

// ---------------- finalize scalars ----------------
__global__ void final_kernel(const double* __restrict__ sse_parts,
                             const double* __restrict__ perp,
                             const double* __restrict__ ent,
                             const double* __restrict__ uniq,
                             float* __restrict__ out, int N) {
  int l = threadIdx.x;
  double s = sse_parts[l];
  #pragma unroll
  for (int off = 1; off < 64; off <<= 1) s += __shfl_xor(s, off, 64);
  if (l == 0 && blockIdx.x == 0) {
    double mp = 0.0, me = 0.0, mu = 0.0;
    for (int b = 0; b < NBATCH; ++b) { mp += perp[b]; me += ent[b]; mu += uniq[b]; }
    mp /= NBATCH; me /= NBATCH; mu /= NBATCH;
    double loss = s / ((double)N * (double)D64);
    size_t voff = (size_t)N * D64;
    size_t coff = voff + 1;
    size_t poff = coff + 1 + (size_t)N;
    out[voff] = (float)loss;
    out[coff] = (float)loss;
    out[poff] = (float)mp;
    out[poff + 1] = (float)me;
    out[poff + 2] = (float)mu;
  }
}

extern "C" void kernel_launch(void* const* d_in, const int* in_sizes, int n_in,
                              void* d_out, int out_size, void* d_ws, size_t ws_size,
                              hipStream_t stream) {
  const float* z = (const float*)d_in[0];
  const int* bid = (const int*)d_in[1];
  const float* cb = (const float*)d_in[2];
  int N = in_sizes[1];
  int Dd = in_sizes[0] / N;
  int K = in_sizes[2] / Dd;
  float* out = (float*)d_out;

  // workspace layout (256B-aligned chunks); total ~34 MB
  char* ws = (char*)d_ws;
  size_t off = 0;
  auto alloc = [&](size_t bytes) {
    void* p = ws + off;
    off += (bytes + 255) & ~(size_t)255;
    return p;
  };
  unsigned int* counts = (unsigned int*)alloc((size_t)NBATCH * K * 4);
  double* sse_parts = (double*)alloc(64 * 8);
  double* perp = (double*)alloc(8 * NBATCH);
  double* ent  = (double*)alloc(8 * NBATCH);
  double* uniq = (double*)alloc(8 * NBATCH);
  float* csq = (float*)alloc((size_t)K * 4);
  short* cbh = (short*)alloc((size_t)K * D64 * 2);
  float* pmin = (float*)alloc((size_t)N * 4);
  unsigned short* bm = (unsigned short*)alloc((size_t)N * NGRP * 2);

  size_t ioff = (size_t)N * Dd + 2;

  csq_cvt_kernel<<<(K * 64 + 255) / 256, 256, 0, stream>>>(
      cb, csq, cbh, counts, sse_parts, K);
  sweep_kernel<<<N / 128, 256, 0, stream>>>(z, cbh, csq, bm, pmin, N, K);
  rescore_wave_kernel<<<N / 4, 256, 0, stream>>>(
      z, cb, csq, bm, pmin, bid, out + ioff, out, counts, sse_parts, N, K);
  stats_kernel<<<NBATCH, 256, 0, stream>>>(counts, perp, ent, uniq, K);
  final_kernel<<<1, 64, 0, stream>>>(sse_parts, perp, ent, uniq, out, N);
}